// Round 4
// baseline (7081.120 us; speedup 1.0000x reference)
//
#include <hip/hip_runtime.h>

// ============================================================================
// GRU_29300266893722  (B=64, T=512, IN=256, H=1024, OUT=256)  -- MI355X gfx950
//
// R4: MALL-resident exchange. Same 4 chains x 16 blocks structure as R3, but:
//  - data + sentinels published with non-returning global_atomic_swap
//    (device-scope atomics execute at the coherence point and keep the line
//    in MALL SRAM -> no DRAM write-through / re-fetch, which R3's counters
//    showed: WRITE_SIZE 264 MB == exchange stores, FETCH 1.15 GB).
//  - per-wave sentinels (64/chain) gate consumption: 64 B/wave poll rounds
//    instead of 16 KB/wave; tag-in-data retained as correctness backstop.
//  - phase-B Vr weights prefetched via pipelined asm loads issued before the
//    spin (ct0/1) and right after data lands (ct2/3) -> off critical path.
// ============================================================================

#define BB 64
#define TT 512
#define KIN 256
#define HH 1024
#define NOUT 256

typedef float  f32x4 __attribute__((ext_vector_type(4)));
typedef short  s16x8 __attribute__((ext_vector_type(8)));
typedef unsigned int u32x4 __attribute__((ext_vector_type(4)));
typedef unsigned short u16x4 __attribute__((ext_vector_type(4)));

#define MFMA16(a, b, c) __builtin_amdgcn_mfma_f32_16x16x32_bf16((a), (b), (c), 0, 0, 0)

static __device__ __forceinline__ s16x8 as16(u32x4 v) { return __builtin_bit_cast(s16x8, v); }

static __device__ __forceinline__ unsigned short f2bf(float f) {
  unsigned u = __float_as_uint(f);
  u += 0x7FFFu + ((u >> 16) & 1u);   // round-to-nearest-even
  return (unsigned short)(u >> 16);
}
static __device__ __forceinline__ float bf2f(unsigned short h) {
  return __uint_as_float(((unsigned)h) << 16);
}

static __device__ __forceinline__ float tanh_fast(float x) {
  float xc = fminf(fmaxf(x, -15.f), 15.f);
  float e = __expf(2.f * xc);
  return (e - 1.f) / (e + 1.f);
}
static __device__ __forceinline__ float sigmoid_fast(float x) {
  float xc = fminf(fmaxf(x, -30.f), 30.f);
  return 1.f / (1.f + __expf(-xc));
}

// ---- exchange primitives ---------------------------------------------------
// Non-returning device-scope atomic swap: executes at the coherence point,
// line stays MALL-resident (no DRAM write-through).
static __device__ __forceinline__ void at_swap(unsigned* p, unsigned v) {
  asm volatile("global_atomic_swap %0, %1, off" :: "v"(p), "v"(v) : "memory");
}
// sc0sc1 load: bypass L1/L2, read at coherence point (sees atomic results).
template <int OFF>
static __device__ __forceinline__ void ld128o(u32x4& d, const unsigned* p) {
  asm volatile("global_load_dwordx4 %0, %1, off offset:%2 sc0 sc1"
               : "=v"(d) : "v"(p), "i"(OFF));
}
// plain cached load (L2) for weight streaming, hand-placed so it can be
// issued across the spin's memory clobbers
static __device__ __forceinline__ void ldp128(u32x4& d, const void* p) {
  asm volatile("global_load_dwordx4 %0, %1, off" : "=v"(d) : "v"(p));
}
static __device__ __forceinline__ void tie16(u32x4& a0, u32x4& a1, u32x4& a2, u32x4& a3,
                                             u32x4& a4, u32x4& a5, u32x4& a6, u32x4& a7,
                                             u32x4& a8, u32x4& a9, u32x4& aA, u32x4& aB,
                                             u32x4& aC, u32x4& aD, u32x4& aE, u32x4& aF) {
  asm volatile("s_waitcnt vmcnt(0)"
               : "+v"(a0), "+v"(a1), "+v"(a2), "+v"(a3),
                 "+v"(a4), "+v"(a5), "+v"(a6), "+v"(a7),
                 "+v"(a8), "+v"(a9), "+v"(aA), "+v"(aB),
                 "+v"(aC), "+v"(aD), "+v"(aE), "+v"(aF)
               :: "memory");
}

// pack two tagged-dword quads into one bf16x8 fragment register quad
static __device__ __forceinline__ unsigned pk(unsigned hi, unsigned lo) {
  return __builtin_amdgcn_perm(hi, lo, 0x07060302u);
}
static __device__ __forceinline__ u32x4 pack_frag(u32x4 a, u32x4 b) {
  u32x4 r;
  r.x = pk(a.y, a.x); r.y = pk(a.w, a.z);
  r.z = pk(b.y, b.x); r.w = pk(b.w, b.z);
  return r;
}

// Cheap gate: poll the chain's 64 per-wave sentinels (lane i polls sentinel i)
// until all == tag. Returns true on timeout.
static __device__ __forceinline__ bool spin_sent(const unsigned* s, int lane, unsigned tag,
                                                 bool dead) {
  if (dead) return true;
  int guard = 0;
  while (true) {
    unsigned v;
    asm volatile("global_load_dword %0, %1, off sc0 sc1\n\ts_waitcnt vmcnt(0)"
                 : "=v"(v) : "v"(s + lane) : "memory");
    if (__all(v == tag)) return false;
    if (++guard > (1 << 20)) return true;
  }
}

// Tag-validated A-operand load (correctness backstop; usually 1 round after
// the sentinel gate).
static __device__ __forceinline__ void load_validated(
    const unsigned* rp, unsigned tag, bool& dead, u32x4 (&a)[8]) {
  u32x4 r0, r1, r2, r3, r4, r5, r6, r7, r8, r9, rA, rB, rC, rD, rE, rF;
  int guard = 0;
  while (true) {
    ld128o<0 * 4>(r0, rp);   ld128o<4 * 4>(r1, rp);
    ld128o<32 * 4>(r2, rp);  ld128o<36 * 4>(r3, rp);
    ld128o<64 * 4>(r4, rp);  ld128o<68 * 4>(r5, rp);
    ld128o<96 * 4>(r6, rp);  ld128o<100 * 4>(r7, rp);
    ld128o<128 * 4>(r8, rp); ld128o<132 * 4>(r9, rp);
    ld128o<160 * 4>(rA, rp); ld128o<164 * 4>(rB, rp);
    ld128o<192 * 4>(rC, rp); ld128o<196 * 4>(rD, rp);
    ld128o<224 * 4>(rE, rp); ld128o<228 * 4>(rF, rp);
    tie16(r0, r1, r2, r3, r4, r5, r6, r7, r8, r9, rA, rB, rC, rD, rE, rF);
    unsigned bad = 0;
#define CHK(R) bad |= (R.x ^ tag) | (R.y ^ tag) | (R.z ^ tag) | (R.w ^ tag)
    CHK(r0); CHK(r1); CHK(r2); CHK(r3); CHK(r4); CHK(r5); CHK(r6); CHK(r7);
    CHK(r8); CHK(r9); CHK(rA); CHK(rB); CHK(rC); CHK(rD); CHK(rE); CHK(rF);
#undef CHK
    bad &= 0xFFFFu;
    if (__all(bad == 0)) break;
    if (dead || ++guard > 4096) { dead = true; break; }
  }
  a[0] = pack_frag(r0, r1); a[1] = pack_frag(r2, r3);
  a[2] = pack_frag(r4, r5); a[3] = pack_frag(r6, r7);
  a[4] = pack_frag(r8, r9); a[5] = pack_frag(rA, rB);
  a[6] = pack_frag(rC, rD); a[7] = pack_frag(rE, rF);
}

// ---- workspace layout ------------------------------------------------------
static constexpr size_t SZ_XP   = (size_t)TT * BB * HH * 2;       // 64 MB
static constexpr size_t OFF_XH  = 0;
static constexpr size_t OFF_XZ  = OFF_XH + SZ_XP;
static constexpr size_t OFF_XR  = OFF_XZ + SZ_XP;
static constexpr size_t OFF_XB  = OFF_XR + SZ_XP;                 // X bf16
static constexpr size_t OFF_WHP = OFF_XB + (size_t)BB * TT * KIN * 2;
static constexpr size_t OFF_VZP = OFF_WHP + (size_t)HH * HH * 2;
static constexpr size_t OFF_VRP = OFF_VZP + (size_t)HH * HH * 2;
static constexpr size_t OFF_WXP = OFF_VRP + (size_t)HH * HH * 2;
static constexpr size_t OFF_UZP = OFF_WXP + (size_t)HH * KIN * 2;
static constexpr size_t OFF_URP = OFF_UZP + (size_t)HH * KIN * 2;
static constexpr size_t OFF_HB  = OFF_URP + (size_t)HH * KIN * 2; // 4*16*1024 tagged dwords
static constexpr size_t OFF_HRB = OFF_HB + (size_t)4 * 16 * HH * 4;
static constexpr size_t OFF_SA  = OFF_HRB + (size_t)4 * 16 * HH * 4;  // 4*64 dwords
static constexpr size_t OFF_SB  = OFF_SA + 1024;
static constexpr size_t OFF_HF  = OFF_SB + 1024;                  // final h fp32

// ============================================================================
// K1: X fp32 -> bf16
// ============================================================================
__global__ void __launch_bounds__(256) k_convert_x(const float* __restrict__ X,
                                                   unsigned short* __restrict__ Xb) {
  size_t i = ((size_t)blockIdx.x * 256 + threadIdx.x) * 4;
  f32x4 v = *(const f32x4*)(X + i);
  u16x4 o = { f2bf(v[0]), f2bf(v[1]), f2bf(v[2]), f2bf(v[3]) };
  *(u16x4*)(Xb + i) = o;
}

// ============================================================================
// K2: pack weights W[1024][K] fp32 -> bf16 MFMA B-fragment layout
// ============================================================================
__global__ void __launch_bounds__(256) k_pack_w(
    const float* __restrict__ Wh, const float* __restrict__ Vz, const float* __restrict__ Vr,
    const float* __restrict__ Wx, const float* __restrict__ Uz, const float* __restrict__ Ur,
    unsigned short* __restrict__ Whp, unsigned short* __restrict__ Vzp, unsigned short* __restrict__ Vrp,
    unsigned short* __restrict__ Wxp, unsigned short* __restrict__ Uzp, unsigned short* __restrict__ Urp) {
  int z = blockIdx.y;
  const float* src; unsigned short* dst; int K;
  switch (z) {
    case 0: src = Wh; dst = Whp; K = 1024; break;
    case 1: src = Vz; dst = Vzp; K = 1024; break;
    case 2: src = Vr; dst = Vrp; K = 1024; break;
    case 3: src = Wx; dst = Wxp; K = 256;  break;
    case 4: src = Uz; dst = Uzp; K = 256;  break;
    default: src = Ur; dst = Urp; K = 256; break;
  }
  int KK = K >> 5;
  int total = 64 * KK * 64;
  int tau = blockIdx.x * 256 + threadIdx.x;
  if (tau >= total) return;
  int lane = tau & 63;
  int kk = (tau >> 6) % KK;
  int ct = tau / (KK * 64);
  int q = lane >> 4, cl = lane & 15;
  const float* s = src + (size_t)(ct * 16 + cl) * K + kk * 32 + q * 8;
  f32x4 v0 = *(const f32x4*)s;
  f32x4 v1 = *(const f32x4*)(s + 4);
  u32x4 o;
  o.x = (unsigned)f2bf(v0[0]) | ((unsigned)f2bf(v0[1]) << 16);
  o.y = (unsigned)f2bf(v0[2]) | ((unsigned)f2bf(v0[3]) << 16);
  o.z = (unsigned)f2bf(v1[0]) | ((unsigned)f2bf(v1[1]) << 16);
  o.w = (unsigned)f2bf(v1[2]) | ((unsigned)f2bf(v1[3]) << 16);
  *(u32x4*)(dst + (size_t)tau * 8) = o;
}

// ============================================================================
// K3: XH/XZ/XR[t][b][h] (bf16) = X @ {Wx,Uz,Ur}^T + bias.  grid (512,16,3).
// ============================================================================
__global__ void __launch_bounds__(256) k_proj(
    const unsigned short* __restrict__ Xb,
    const unsigned short* __restrict__ Wxp, const unsigned short* __restrict__ Uzp,
    const unsigned short* __restrict__ Urp,
    const float* __restrict__ bx, const float* __restrict__ bz, const float* __restrict__ br,
    unsigned short* __restrict__ XH, unsigned short* __restrict__ XZ, unsigned short* __restrict__ XR) {
  __shared__ u32x4 As[4 * 8 * 64];  // 32 KB
  const int tid = threadIdx.x;
  const int mb = blockIdx.x, cb = blockIdx.y, mu = blockIdx.z;

#pragma unroll
  for (int i = 0; i < 8; ++i) {
    int fid = i * 256 + tid;
    int lane = fid & 63, kk = (fid >> 6) & 7, rt = fid >> 9;
    int q = lane >> 4, cl = lane & 15;
    int mrow = mb * 64 + rt * 16 + cl;
    As[fid] = *(const u32x4*)(Xb + (size_t)mrow * KIN + kk * 32 + q * 8);
  }
  __syncthreads();

  const int lane = tid & 63, w = tid >> 6;
  const int q = lane >> 4, cl = lane & 15;
  const unsigned short* Bp = (mu == 0) ? Wxp : (mu == 1) ? Uzp : Urp;
  const float* bias        = (mu == 0) ? bx  : (mu == 1) ? bz  : br;
  unsigned short* Dst      = (mu == 0) ? XH  : (mu == 1) ? XZ  : XR;

  f32x4 z4 = {0.f, 0.f, 0.f, 0.f};
  f32x4 acc[4] = {z4, z4, z4, z4};
  const int ctg = cb * 4 + w;
#pragma unroll
  for (int kk = 0; kk < 8; ++kk) {
    u32x4 b = *(const u32x4*)(Bp + ((size_t)(ctg * 8 + kk) * 64 + lane) * 8);
#pragma unroll
    for (int rt = 0; rt < 4; ++rt)
      acc[rt] = MFMA16(as16(As[(rt * 8 + kk) * 64 + lane]), as16(b), acc[rt]);
  }
  const int col = cb * 64 + w * 16 + cl;
  const float bv = bias[col];
#pragma unroll
  for (int rt = 0; rt < 4; ++rt) {
#pragma unroll
    for (int j = 0; j < 4; ++j) {
      int m = mb * 64 + rt * 16 + q * 4 + j;   // m = b*512 + t
      int t = m & (TT - 1), b = m >> 9;
      Dst[((size_t)t * BB + b) * HH + col] = f2bf(acc[rt][j] + bv);
    }
  }
}

// ============================================================================
// K4: persistent scan, MALL-resident tag-in-data + per-wave sentinels.
//   64 blocks x 256 threads. chain g = blk>>4, col-block c = blk&15, wave w:
//   K-slice [256w,256w+256), owns state for cols c*64+w*16+cl, rows q*4+j.
// ============================================================================
__global__ void __launch_bounds__(256, 1) k_scan(
    const unsigned short* __restrict__ XH, const unsigned short* __restrict__ XZ,
    const unsigned short* __restrict__ XR,
    const unsigned short* __restrict__ Whp, const unsigned short* __restrict__ Vzp,
    const unsigned short* __restrict__ Vrp,
    unsigned* __restrict__ hb32all, unsigned* __restrict__ hrb32all,
    unsigned* __restrict__ sAall, unsigned* __restrict__ sBall,
    float* __restrict__ hfinal) {
  __shared__ f32x4 redA[16 * 64];  // 16 KB
  __shared__ f32x4 redB[16 * 64];  // 16 KB
  __shared__ f32x4 redC[16 * 64];  // 16 KB

  const int tid = threadIdx.x;
  const int lane = tid & 63, w = tid >> 6;
  const int q = lane >> 4, cl = lane & 15;
  const int blk = blockIdx.x;
  const int g = blk >> 4, c = blk & 15;   // chain, col-block
  const int c4 = c * 4, kw = w * 8;

  unsigned* hb  = hb32all  + (size_t)g * 16 * HH;
  unsigned* hrb = hrb32all + (size_t)g * 16 * HH;
  unsigned* sA = sAall + g * 64;
  unsigned* sB = sBall + g * 64;
  const int sidx = c * 4 + w;   // this wave's sentinel slot

  // resident weight fragments: Wh + Vz (256 VGPRs); Vr pipelined from L2
  u32x4 wh[4][8], vz[4][8];
#pragma unroll
  for (int ct = 0; ct < 4; ++ct)
#pragma unroll
    for (int k = 0; k < 8; ++k) {
      size_t fi = (((size_t)(c4 + ct) * 32 + kw + k) * 64 + lane) * 8;
      wh[ct][k] = *(const u32x4*)(Whp + fi);
      vz[ct][k] = *(const u32x4*)(Vzp + fi);
    }

  const int hcol = c * 64 + w * 16 + cl;         // owned output column
  const int brow0 = g * 16 + q * 4;              // owned batch rows (+j)
  const unsigned* rpA = hrb + (size_t)cl * HH + kw * 32 + q * 8;  // A-frag read base
  const unsigned* rpB = hb  + (size_t)cl * HH + kw * 32 + q * 8;
  unsigned* spA = hb  + (size_t)(q * 4) * HH + hcol;   // store base (rows q*4+j)
  unsigned* spB = hrb + (size_t)(q * 4) * HH + hcol;

#define VRADDR(ct, k) (Vrp + (((size_t)(c4 + (ct)) * 32 + kw + (k)) * 64 + lane) * 8)

  const f32x4 z4 = {0.f, 0.f, 0.f, 0.f};
  f32x4 hreg = z4, zreg = z4;
  bool dead = false;

  for (int t = 0; t < TT; ++t) {
    // ---------------- phase A: h update ----------------
    unsigned short xh_u[4];
#pragma unroll
    for (int j = 0; j < 4; ++j)
      xh_u[j] = XH[((size_t)t * BB + brow0 + j) * HH + hcol];

    f32x4 acc[4] = {z4, z4, z4, z4};
    if (t > 0) {
      if (spin_sent(sB, lane, (unsigned)t, dead)) dead = true;
      u32x4 a[8];
      load_validated(rpA, (unsigned)t, dead, a);
#pragma unroll
      for (int k = 0; k < 8; ++k) {
        s16x8 av = as16(a[k]);
#pragma unroll
        for (int ct = 0; ct < 4; ++ct)
          acc[ct] = MFMA16(av, as16(wh[ct][k]), acc[ct]);
      }
    }
#pragma unroll
    for (int ct = 0; ct < 4; ++ct) redA[(w * 4 + ct) * 64 + lane] = acc[ct];
    __syncthreads();
    f32x4 S = redA[(0 * 4 + w) * 64 + lane];
    S += redA[(1 * 4 + w) * 64 + lane];
    S += redA[(2 * 4 + w) * 64 + lane];
    S += redA[(3 * 4 + w) * 64 + lane];

    const unsigned tagn = (unsigned)(t + 1);
    if (t == TT - 1) {
#pragma unroll
      for (int j = 0; j < 4; ++j) {
        float pre = S[j] + bf2f(xh_u[j]);
        float ht = tanh_fast(pre);
        hreg[j] = zreg[j] * hreg[j] + (1.f - zreg[j]) * ht;
      }
      break;
    }
#pragma unroll
    for (int j = 0; j < 4; ++j) {
      float pre = S[j] + bf2f(xh_u[j]);
      float ht = tanh_fast(pre);
      float hn = zreg[j] * hreg[j] + (1.f - zreg[j]) * ht;
      hreg[j] = hn;
      at_swap(spA + (size_t)j * HH, ((unsigned)f2bf(hn) << 16) | tagn);
    }
    if (lane == 0) at_swap(sA + sidx, tagn);   // per-wave publish, no barrier

    // ---------------- phase B: gates ----------------
    // prefetch Vr ct0/ct1 (independent of exchange -> issued before the spin)
    u32x4 p0, p1, p2, p3, p4, p5, p6, p7, p8, p9, pA, pB, pC, pD, pE, pF;
    ldp128(p0, VRADDR(0, 0)); ldp128(p1, VRADDR(0, 1));
    ldp128(p2, VRADDR(0, 2)); ldp128(p3, VRADDR(0, 3));
    ldp128(p4, VRADDR(0, 4)); ldp128(p5, VRADDR(0, 5));
    ldp128(p6, VRADDR(0, 6)); ldp128(p7, VRADDR(0, 7));
    ldp128(p8, VRADDR(1, 0)); ldp128(p9, VRADDR(1, 1));
    ldp128(pA, VRADDR(1, 2)); ldp128(pB, VRADDR(1, 3));
    ldp128(pC, VRADDR(1, 4)); ldp128(pD, VRADDR(1, 5));
    ldp128(pE, VRADDR(1, 6)); ldp128(pF, VRADDR(1, 7));

    unsigned short xz_u[4], xr_u[4];
#pragma unroll
    for (int j = 0; j < 4; ++j) {
      xz_u[j] = XZ[((size_t)t * BB + brow0 + j) * HH + hcol];
      xr_u[j] = XR[((size_t)t * BB + brow0 + j) * HH + hcol];
    }
    if (spin_sent(sA, lane, tagn, dead)) dead = true;
    u32x4 b[8];
    load_validated(rpB, tagn, dead, b);

    // issue Vr ct2/ct3 now; they land under the az MFMAs
    u32x4 q0, q1, q2, q3, q4, q5, q6, q7, q8, q9, qA, qB, qC, qD, qE, qF;
    ldp128(q0, VRADDR(2, 0)); ldp128(q1, VRADDR(2, 1));
    ldp128(q2, VRADDR(2, 2)); ldp128(q3, VRADDR(2, 3));
    ldp128(q4, VRADDR(2, 4)); ldp128(q5, VRADDR(2, 5));
    ldp128(q6, VRADDR(2, 6)); ldp128(q7, VRADDR(2, 7));
    ldp128(q8, VRADDR(3, 0)); ldp128(q9, VRADDR(3, 1));
    ldp128(qA, VRADDR(3, 2)); ldp128(qB, VRADDR(3, 3));
    ldp128(qC, VRADDR(3, 4)); ldp128(qD, VRADDR(3, 5));
    ldp128(qE, VRADDR(3, 6)); ldp128(qF, VRADDR(3, 7));

    f32x4 az[4] = {z4, z4, z4, z4};
#pragma unroll
    for (int k = 0; k < 8; ++k) {
      s16x8 av = as16(b[k]);
#pragma unroll
      for (int ct = 0; ct < 4; ++ct)
        az[ct] = MFMA16(av, as16(vz[ct][k]), az[ct]);
    }

    f32x4 ar[4] = {z4, z4, z4, z4};
    tie16(p0, p1, p2, p3, p4, p5, p6, p7, p8, p9, pA, pB, pC, pD, pE, pF);
    {
      u32x4 vr0[8] = {p0, p1, p2, p3, p4, p5, p6, p7};
      u32x4 vr1[8] = {p8, p9, pA, pB, pC, pD, pE, pF};
#pragma unroll
      for (int k = 0; k < 8; ++k) {
        ar[0] = MFMA16(as16(b[k]), as16(vr0[k]), ar[0]);
        ar[1] = MFMA16(as16(b[k]), as16(vr1[k]), ar[1]);
      }
    }
    tie16(q0, q1, q2, q3, q4, q5, q6, q7, q8, q9, qA, qB, qC, qD, qE, qF);
    {
      u32x4 vr2[8] = {q0, q1, q2, q3, q4, q5, q6, q7};
      u32x4 vr3[8] = {q8, q9, qA, qB, qC, qD, qE, qF};
#pragma unroll
      for (int k = 0; k < 8; ++k) {
        ar[2] = MFMA16(as16(b[k]), as16(vr2[k]), ar[2]);
        ar[3] = MFMA16(as16(b[k]), as16(vr3[k]), ar[3]);
      }
    }

#pragma unroll
    for (int ct = 0; ct < 4; ++ct) {
      redB[(w * 4 + ct) * 64 + lane] = az[ct];
      redC[(w * 4 + ct) * 64 + lane] = ar[ct];
    }
    __syncthreads();
    f32x4 Sz = redB[(0 * 4 + w) * 64 + lane];
    Sz += redB[(1 * 4 + w) * 64 + lane];
    Sz += redB[(2 * 4 + w) * 64 + lane];
    Sz += redB[(3 * 4 + w) * 64 + lane];
    f32x4 Sr = redC[(0 * 4 + w) * 64 + lane];
    Sr += redC[(1 * 4 + w) * 64 + lane];
    Sr += redC[(2 * 4 + w) * 64 + lane];
    Sr += redC[(3 * 4 + w) * 64 + lane];

#pragma unroll
    for (int j = 0; j < 4; ++j) {
      float zv = sigmoid_fast(Sz[j] + bf2f(xz_u[j]));
      float rv = sigmoid_fast(Sr[j] + bf2f(xr_u[j]));
      zreg[j] = zv;
      at_swap(spB + (size_t)j * HH, ((unsigned)f2bf(rv * hreg[j]) << 16) | tagn);
    }
    if (lane == 0) at_swap(sB + sidx, tagn);
  }

  // epilogue: final h fp32 (plain stores; visible at kernel boundary)
#pragma unroll
  for (int j = 0; j < 4; ++j)
    hfinal[(size_t)(brow0 + j) * HH + hcol] = hreg[j];
#undef VRADDR
}

// ============================================================================
// K5: out[b][o] = dot(h[b,:], Wo[o,:]) + bo[o]   (fp32)
// ============================================================================
__global__ void __launch_bounds__(256) k_out(const float* __restrict__ hf,
                                             const float* __restrict__ Wo,
                                             const float* __restrict__ bo,
                                             float* __restrict__ out) {
  __shared__ float hs[HH];
  const int b = blockIdx.x, tid = threadIdx.x;
  *(f32x4*)&hs[tid * 4] = *(const f32x4*)(hf + (size_t)b * HH + tid * 4);
  __syncthreads();
  float acc = bo[tid];
  const f32x4* wr = (const f32x4*)(Wo + (size_t)tid * HH);
#pragma unroll 8
  for (int k = 0; k < HH / 4; ++k) {
    f32x4 wv = wr[k];
    f32x4 hv = *(const f32x4*)&hs[k * 4];
    acc += wv[0] * hv[0] + wv[1] * hv[1] + wv[2] * hv[2] + wv[3] * hv[3];
  }
  out[(size_t)b * NOUT + tid] = acc;
}

// ============================================================================
extern "C" void kernel_launch(void* const* d_in, const int* in_sizes, int n_in,
                              void* d_out, int out_size, void* d_ws, size_t ws_size,
                              hipStream_t stream) {
  (void)in_sizes; (void)n_in; (void)out_size; (void)ws_size;
  const float* X  = (const float*)d_in[0];
  const float* Wx = (const float*)d_in[1];
  const float* bx = (const float*)d_in[2];
  const float* Wh = (const float*)d_in[3];
  const float* Uz = (const float*)d_in[4];
  const float* bz = (const float*)d_in[5];
  const float* Vz = (const float*)d_in[6];
  const float* Ur = (const float*)d_in[7];
  const float* br = (const float*)d_in[8];
  const float* Vr = (const float*)d_in[9];
  const float* Wo = (const float*)d_in[10];
  const float* bo = (const float*)d_in[11];

  char* ws = (char*)d_ws;
  unsigned short* XHp = (unsigned short*)(ws + OFF_XH);
  unsigned short* XZp = (unsigned short*)(ws + OFF_XZ);
  unsigned short* XRp = (unsigned short*)(ws + OFF_XR);
  unsigned short* Xb  = (unsigned short*)(ws + OFF_XB);
  unsigned short* Whp = (unsigned short*)(ws + OFF_WHP);
  unsigned short* Vzp = (unsigned short*)(ws + OFF_VZP);
  unsigned short* Vrp = (unsigned short*)(ws + OFF_VRP);
  unsigned short* Wxp = (unsigned short*)(ws + OFF_WXP);
  unsigned short* Uzp = (unsigned short*)(ws + OFF_UZP);
  unsigned short* Urp = (unsigned short*)(ws + OFF_URP);
  unsigned* hbp  = (unsigned*)(ws + OFF_HB);
  unsigned* hrbp = (unsigned*)(ws + OFF_HRB);
  unsigned* sAp  = (unsigned*)(ws + OFF_SA);
  unsigned* sBp  = (unsigned*)(ws + OFF_SB);
  float* hfp = (float*)(ws + OFF_HF);

  k_convert_x<<<8192, 256, 0, stream>>>(X, Xb);
  k_pack_w<<<dim3(512, 6), 256, 0, stream>>>(Wh, Vz, Vr, Wx, Uz, Ur,
                                             Whp, Vzp, Vrp, Wxp, Uzp, Urp);
  k_proj<<<dim3(512, 16, 3), 256, 0, stream>>>(Xb, Wxp, Uzp, Urp, bx, bz, br,
                                               XHp, XZp, XRp);
  k_scan<<<64, 256, 0, stream>>>(XHp, XZp, XRp, Whp, Vzp, Vrp,
                                 hbp, hrbp, sAp, sBp, hfp);
  k_out<<<64, 256, 0, stream>>>(hfp, Wo, bo, (float*)d_out);
}

// Round 5
// 4042.637 us; speedup vs baseline: 1.7516x; 1.7516x over previous
//
#include <hip/hip_runtime.h>

// ============================================================================
// GRU_29300266893722  (B=64, T=512, IN=256, H=1024, OUT=256)  -- MI355X gfx950
//
// R5: R3 protocol (tag-in-data, fire-and-forget sc0sc1 stores, validated
// loads) with the exchange buffers stored in CONSUMER FRAGMENT-MAJOR layout:
//   dword index (w,k,half,lane,jm) = (w*8+k)*512 + half*256 + lane*4 + jm
//   holds tagged h[row=lane&15][col = 256w + 32k + 8*(lane>>4) + half*4+jm]
// -> each consumer ld128 is contiguous (1KB span, 16 lines) instead of
//    row-strided (64 lines). R3's gather was 1024 line-transactions per
//    wave per validation round; this is 256, sequential.
// R4's sentinels/atomics reverted (regressed: +1.8ms, WRITE/FETCH unchanged
// -> atomics don't change residency; extra gate RT + retry rounds hurt).
// ============================================================================

#define BB 64
#define TT 512
#define KIN 256
#define HH 1024
#define NOUT 256

typedef float  f32x4 __attribute__((ext_vector_type(4)));
typedef short  s16x8 __attribute__((ext_vector_type(8)));
typedef unsigned int u32x4 __attribute__((ext_vector_type(4)));
typedef unsigned short u16x4 __attribute__((ext_vector_type(4)));

#define MFMA16(a, b, c) __builtin_amdgcn_mfma_f32_16x16x32_bf16((a), (b), (c), 0, 0, 0)

static __device__ __forceinline__ s16x8 as16(u32x4 v) { return __builtin_bit_cast(s16x8, v); }

static __device__ __forceinline__ unsigned short f2bf(float f) {
  unsigned u = __float_as_uint(f);
  u += 0x7FFFu + ((u >> 16) & 1u);   // round-to-nearest-even
  return (unsigned short)(u >> 16);
}
static __device__ __forceinline__ float bf2f(unsigned short h) {
  return __uint_as_float(((unsigned)h) << 16);
}

static __device__ __forceinline__ float tanh_fast(float x) {
  float xc = fminf(fmaxf(x, -15.f), 15.f);
  float e = __expf(2.f * xc);
  return (e - 1.f) / (e + 1.f);
}
static __device__ __forceinline__ float sigmoid_fast(float x) {
  float xc = fminf(fmaxf(x, -30.f), 30.f);
  return 1.f / (1.f + __expf(-xc));
}

// ---- device-scope (IF-coherent) access helpers -----------------------------
static __device__ __forceinline__ void st_dw(unsigned* p, unsigned v) {
  asm volatile("global_store_dword %0, %1, off sc0 sc1" :: "v"(p), "v"(v) : "memory");
}
template <int OFF>
static __device__ __forceinline__ void ld128o(u32x4& d, const unsigned* p) {
  asm volatile("global_load_dwordx4 %0, %1, off offset:%2 sc0 sc1"
               : "=v"(d) : "v"(p), "i"(OFF));
}
static __device__ __forceinline__ void tie16(u32x4& a0, u32x4& a1, u32x4& a2, u32x4& a3,
                                             u32x4& a4, u32x4& a5, u32x4& a6, u32x4& a7,
                                             u32x4& a8, u32x4& a9, u32x4& aA, u32x4& aB,
                                             u32x4& aC, u32x4& aD, u32x4& aE, u32x4& aF) {
  asm volatile("s_waitcnt vmcnt(0)"
               : "+v"(a0), "+v"(a1), "+v"(a2), "+v"(a3),
                 "+v"(a4), "+v"(a5), "+v"(a6), "+v"(a7),
                 "+v"(a8), "+v"(a9), "+v"(aA), "+v"(aB),
                 "+v"(aC), "+v"(aD), "+v"(aE), "+v"(aF)
               :: "memory");
}

// pack two tagged-dword quads (cols j0..3, j4..7) into one bf16x8 frag quad
static __device__ __forceinline__ unsigned pk(unsigned hi, unsigned lo) {
  return __builtin_amdgcn_perm(hi, lo, 0x07060302u);
}
static __device__ __forceinline__ u32x4 pack_frag(u32x4 a, u32x4 b) {
  u32x4 r;
  r.x = pk(a.y, a.x); r.y = pk(a.w, a.z);
  r.z = pk(b.y, b.x); r.w = pk(b.w, b.z);
  return r;
}

// Validated A-operand load, fragment-major layout. rp0 = buf + w*4096 + lane*4
// (dwords). Frag k: lo at k*2048B, hi at +1024B; 4 base pointers keep the
// 13-bit signed immediate offsets in range. Retries until all tags match.
static __device__ __forceinline__ void load_validated(
    const unsigned* rp0, unsigned tag, bool& dead, u32x4 (&a)[8]) {
  const unsigned* p1 = rp0 + 1024;
  const unsigned* p2 = rp0 + 2048;
  const unsigned* p3 = rp0 + 3072;
  u32x4 r0, r1, r2, r3, r4, r5, r6, r7, r8, r9, rA, rB, rC, rD, rE, rF;
  int guard = 0;
  while (true) {
    ld128o<0>(r0, rp0); ld128o<1024>(r1, rp0); ld128o<2048>(r2, rp0); ld128o<3072>(r3, rp0);
    ld128o<0>(r4, p1);  ld128o<1024>(r5, p1);  ld128o<2048>(r6, p1);  ld128o<3072>(r7, p1);
    ld128o<0>(r8, p2);  ld128o<1024>(r9, p2);  ld128o<2048>(rA, p2);  ld128o<3072>(rB, p2);
    ld128o<0>(rC, p3);  ld128o<1024>(rD, p3);  ld128o<2048>(rE, p3);  ld128o<3072>(rF, p3);
    tie16(r0, r1, r2, r3, r4, r5, r6, r7, r8, r9, rA, rB, rC, rD, rE, rF);
    unsigned bad = 0;
#define CHK(R) bad |= (R.x ^ tag) | (R.y ^ tag) | (R.z ^ tag) | (R.w ^ tag)
    CHK(r0); CHK(r1); CHK(r2); CHK(r3); CHK(r4); CHK(r5); CHK(r6); CHK(r7);
    CHK(r8); CHK(r9); CHK(rA); CHK(rB); CHK(rC); CHK(rD); CHK(rE); CHK(rF);
#undef CHK
    bad &= 0xFFFFu;
    if (__all(bad == 0)) break;
    if (dead || ++guard > 4096) { dead = true; break; }
  }
  a[0] = pack_frag(r0, r1); a[1] = pack_frag(r2, r3);
  a[2] = pack_frag(r4, r5); a[3] = pack_frag(r6, r7);
  a[4] = pack_frag(r8, r9); a[5] = pack_frag(rA, rB);
  a[6] = pack_frag(rC, rD); a[7] = pack_frag(rE, rF);
}

// ---- workspace layout ------------------------------------------------------
static constexpr size_t SZ_XP   = (size_t)TT * BB * HH * 2;       // 64 MB
static constexpr size_t OFF_XH  = 0;
static constexpr size_t OFF_XZ  = OFF_XH + SZ_XP;
static constexpr size_t OFF_XR  = OFF_XZ + SZ_XP;
static constexpr size_t OFF_XB  = OFF_XR + SZ_XP;                 // X bf16
static constexpr size_t OFF_WHP = OFF_XB + (size_t)BB * TT * KIN * 2;
static constexpr size_t OFF_VZP = OFF_WHP + (size_t)HH * HH * 2;
static constexpr size_t OFF_VRP = OFF_VZP + (size_t)HH * HH * 2;
static constexpr size_t OFF_WXP = OFF_VRP + (size_t)HH * HH * 2;
static constexpr size_t OFF_UZP = OFF_WXP + (size_t)HH * KIN * 2;
static constexpr size_t OFF_URP = OFF_UZP + (size_t)HH * KIN * 2;
static constexpr size_t OFF_HB  = OFF_URP + (size_t)HH * KIN * 2; // 4*16*1024 tagged dwords
static constexpr size_t OFF_HRB = OFF_HB + (size_t)4 * 16 * HH * 4;
static constexpr size_t OFF_HF  = OFF_HRB + (size_t)4 * 16 * HH * 4;  // final h fp32

// ============================================================================
// K1: X fp32 -> bf16
// ============================================================================
__global__ void __launch_bounds__(256) k_convert_x(const float* __restrict__ X,
                                                   unsigned short* __restrict__ Xb) {
  size_t i = ((size_t)blockIdx.x * 256 + threadIdx.x) * 4;
  f32x4 v = *(const f32x4*)(X + i);
  u16x4 o = { f2bf(v[0]), f2bf(v[1]), f2bf(v[2]), f2bf(v[3]) };
  *(u16x4*)(Xb + i) = o;
}

// ============================================================================
// K2: pack weights W[1024][K] fp32 -> bf16 MFMA B-fragment layout
// ============================================================================
__global__ void __launch_bounds__(256) k_pack_w(
    const float* __restrict__ Wh, const float* __restrict__ Vz, const float* __restrict__ Vr,
    const float* __restrict__ Wx, const float* __restrict__ Uz, const float* __restrict__ Ur,
    unsigned short* __restrict__ Whp, unsigned short* __restrict__ Vzp, unsigned short* __restrict__ Vrp,
    unsigned short* __restrict__ Wxp, unsigned short* __restrict__ Uzp, unsigned short* __restrict__ Urp) {
  int z = blockIdx.y;
  const float* src; unsigned short* dst; int K;
  switch (z) {
    case 0: src = Wh; dst = Whp; K = 1024; break;
    case 1: src = Vz; dst = Vzp; K = 1024; break;
    case 2: src = Vr; dst = Vrp; K = 1024; break;
    case 3: src = Wx; dst = Wxp; K = 256;  break;
    case 4: src = Uz; dst = Uzp; K = 256;  break;
    default: src = Ur; dst = Urp; K = 256; break;
  }
  int KK = K >> 5;
  int total = 64 * KK * 64;
  int tau = blockIdx.x * 256 + threadIdx.x;
  if (tau >= total) return;
  int lane = tau & 63;
  int kk = (tau >> 6) % KK;
  int ct = tau / (KK * 64);
  int q = lane >> 4, cl = lane & 15;
  const float* s = src + (size_t)(ct * 16 + cl) * K + kk * 32 + q * 8;
  f32x4 v0 = *(const f32x4*)s;
  f32x4 v1 = *(const f32x4*)(s + 4);
  u32x4 o;
  o.x = (unsigned)f2bf(v0[0]) | ((unsigned)f2bf(v0[1]) << 16);
  o.y = (unsigned)f2bf(v0[2]) | ((unsigned)f2bf(v0[3]) << 16);
  o.z = (unsigned)f2bf(v1[0]) | ((unsigned)f2bf(v1[1]) << 16);
  o.w = (unsigned)f2bf(v1[2]) | ((unsigned)f2bf(v1[3]) << 16);
  *(u32x4*)(dst + (size_t)tau * 8) = o;
}

// ============================================================================
// K3: XH/XZ/XR[t][b][h] (bf16) = X @ {Wx,Uz,Ur}^T + bias.  grid (512,16,3).
// ============================================================================
__global__ void __launch_bounds__(256) k_proj(
    const unsigned short* __restrict__ Xb,
    const unsigned short* __restrict__ Wxp, const unsigned short* __restrict__ Uzp,
    const unsigned short* __restrict__ Urp,
    const float* __restrict__ bx, const float* __restrict__ bz, const float* __restrict__ br,
    unsigned short* __restrict__ XH, unsigned short* __restrict__ XZ, unsigned short* __restrict__ XR) {
  __shared__ u32x4 As[4 * 8 * 64];  // 32 KB
  const int tid = threadIdx.x;
  const int mb = blockIdx.x, cb = blockIdx.y, mu = blockIdx.z;

#pragma unroll
  for (int i = 0; i < 8; ++i) {
    int fid = i * 256 + tid;
    int lane = fid & 63, kk = (fid >> 6) & 7, rt = fid >> 9;
    int q = lane >> 4, cl = lane & 15;
    int mrow = mb * 64 + rt * 16 + cl;
    As[fid] = *(const u32x4*)(Xb + (size_t)mrow * KIN + kk * 32 + q * 8);
  }
  __syncthreads();

  const int lane = tid & 63, w = tid >> 6;
  const int q = lane >> 4, cl = lane & 15;
  const unsigned short* Bp = (mu == 0) ? Wxp : (mu == 1) ? Uzp : Urp;
  const float* bias        = (mu == 0) ? bx  : (mu == 1) ? bz  : br;
  unsigned short* Dst      = (mu == 0) ? XH  : (mu == 1) ? XZ  : XR;

  f32x4 z4 = {0.f, 0.f, 0.f, 0.f};
  f32x4 acc[4] = {z4, z4, z4, z4};
  const int ctg = cb * 4 + w;
#pragma unroll
  for (int kk = 0; kk < 8; ++kk) {
    u32x4 b = *(const u32x4*)(Bp + ((size_t)(ctg * 8 + kk) * 64 + lane) * 8);
#pragma unroll
    for (int rt = 0; rt < 4; ++rt)
      acc[rt] = MFMA16(as16(As[(rt * 8 + kk) * 64 + lane]), as16(b), acc[rt]);
  }
  const int col = cb * 64 + w * 16 + cl;
  const float bv = bias[col];
#pragma unroll
  for (int rt = 0; rt < 4; ++rt) {
#pragma unroll
    for (int j = 0; j < 4; ++j) {
      int m = mb * 64 + rt * 16 + q * 4 + j;   // m = b*512 + t
      int t = m & (TT - 1), b = m >> 9;
      Dst[((size_t)t * BB + b) * HH + col] = f2bf(acc[rt][j] + bv);
    }
  }
}

// ============================================================================
// K4: persistent scan, tag-in-data, fragment-major exchange buffers.
//   64 blocks x 256 threads. chain g = blk>>4 (rows 16g..16g+15),
//   col-block c = blk&15 (cols 64c..64c+63). wave w: K-slice [256w,256w+256),
//   owns state for cols c*64+w*16+cl, rows q*4+j (C/D layout).
// ============================================================================
__global__ void __launch_bounds__(256, 1) k_scan(
    const unsigned short* __restrict__ XH, const unsigned short* __restrict__ XZ,
    const unsigned short* __restrict__ XR,
    const unsigned short* __restrict__ Whp, const unsigned short* __restrict__ Vzp,
    const unsigned short* __restrict__ Vrp,
    unsigned* __restrict__ hb32all, unsigned* __restrict__ hrb32all,
    float* __restrict__ hfinal) {
  __shared__ f32x4 redA[16 * 64];  // 16 KB
  __shared__ f32x4 redB[16 * 64];  // 16 KB
  __shared__ f32x4 redC[16 * 64];  // 16 KB

  const int tid = threadIdx.x;
  const int lane = tid & 63, w = tid >> 6;
  const int q = lane >> 4, cl = lane & 15;
  const int blk = blockIdx.x;
  const int g = blk >> 4, c = blk & 15;   // chain, col-block
  const int c4 = c * 4, kw = w * 8;

  unsigned* hb  = hb32all  + (size_t)g * 16 * HH;
  unsigned* hrb = hrb32all + (size_t)g * 16 * HH;

  // resident weight fragments: Wh + Vz (256 VGPRs); Vr streamed per step
  u32x4 wh[4][8], vz[4][8];
#pragma unroll
  for (int ct = 0; ct < 4; ++ct)
#pragma unroll
    for (int k = 0; k < 8; ++k) {
      size_t fi = (((size_t)(c4 + ct) * 32 + kw + k) * 64 + lane) * 8;
      wh[ct][k] = *(const u32x4*)(Whp + fi);
      vz[ct][k] = *(const u32x4*)(Vzp + fi);
    }

  const int hcol = c * 64 + w * 16 + cl;         // owned output column
  const int brow0 = g * 16 + q * 4;              // owned batch rows (+j)

  // consumer read bases (fragment-major): buf + w*4096 + lane*4 dwords
  const unsigned* rpA = hrb + w * 4096 + lane * 4;
  const unsigned* rpB = hb  + w * 4096 + lane * 4;
  // producer store bases: dword idx = (wd*8+kd)*512 + half*256 + laned*4 + jm
  //   wd=C>>8, kd=(C>>5)&7, half=(C>>2)&1, jm=C&3, laned=((C>>3)&3)*16+q*4+j
  const unsigned C = (unsigned)hcol;
  const unsigned sbase = ((C >> 8) * 8 + ((C >> 5) & 7)) * 512 + ((C >> 2) & 1) * 256 +
                         (((C >> 3) & 3) * 16 + q * 4) * 4 + (C & 3);
  unsigned* spA = hb  + sbase;    // row j store at + j*4
  unsigned* spB = hrb + sbase;

  const f32x4 z4 = {0.f, 0.f, 0.f, 0.f};
  f32x4 hreg = z4, zreg = z4;
  bool dead = false;

  for (int t = 0; t < TT; ++t) {
    // ---------------- phase A: h update ----------------
    unsigned short xh_u[4];
#pragma unroll
    for (int j = 0; j < 4; ++j)
      xh_u[j] = XH[((size_t)t * BB + brow0 + j) * HH + hcol];

    f32x4 acc[4] = {z4, z4, z4, z4};
    if (t > 0) {
      u32x4 a[8];
      load_validated(rpA, (unsigned)t, dead, a);
#pragma unroll
      for (int k = 0; k < 8; ++k) {
        s16x8 av = as16(a[k]);
#pragma unroll
        for (int ct = 0; ct < 4; ++ct)
          acc[ct] = MFMA16(av, as16(wh[ct][k]), acc[ct]);
      }
    }
#pragma unroll
    for (int ct = 0; ct < 4; ++ct) redA[(w * 4 + ct) * 64 + lane] = acc[ct];
    __syncthreads();
    f32x4 S = redA[(0 * 4 + w) * 64 + lane];
    S += redA[(1 * 4 + w) * 64 + lane];
    S += redA[(2 * 4 + w) * 64 + lane];
    S += redA[(3 * 4 + w) * 64 + lane];

    const unsigned tagn = (unsigned)(t + 1);
    if (t == TT - 1) {
#pragma unroll
      for (int j = 0; j < 4; ++j) {
        float pre = S[j] + bf2f(xh_u[j]);
        float ht = tanh_fast(pre);
        hreg[j] = zreg[j] * hreg[j] + (1.f - zreg[j]) * ht;
      }
      break;
    }
#pragma unroll
    for (int j = 0; j < 4; ++j) {
      float pre = S[j] + bf2f(xh_u[j]);
      float ht = tanh_fast(pre);
      float hn = zreg[j] * hreg[j] + (1.f - zreg[j]) * ht;
      hreg[j] = hn;
      st_dw(spA + j * 4, ((unsigned)f2bf(hn) << 16) | tagn);
    }

    // ---------------- phase B: gates ----------------
    unsigned short xz_u[4], xr_u[4];
#pragma unroll
    for (int j = 0; j < 4; ++j) {
      xz_u[j] = XZ[((size_t)t * BB + brow0 + j) * HH + hcol];
      xr_u[j] = XR[((size_t)t * BB + brow0 + j) * HH + hcol];
    }
    u32x4 b[8];
    load_validated(rpB, tagn, dead, b);

    f32x4 az[4] = {z4, z4, z4, z4};
    f32x4 ar[4] = {z4, z4, z4, z4};
#pragma unroll
    for (int ct = 0; ct < 4; ++ct) {
      u32x4 vrk[8];
#pragma unroll
      for (int k = 0; k < 8; ++k)
        vrk[k] = *(const u32x4*)(Vrp + (((size_t)(c4 + ct) * 32 + kw + k) * 64 + lane) * 8);
#pragma unroll
      for (int k = 0; k < 8; ++k)
        az[ct] = MFMA16(as16(b[k]), as16(vz[ct][k]), az[ct]);
#pragma unroll
      for (int k = 0; k < 8; ++k)
        ar[ct] = MFMA16(as16(b[k]), as16(vrk[k]), ar[ct]);
    }
#pragma unroll
    for (int ct = 0; ct < 4; ++ct) {
      redB[(w * 4 + ct) * 64 + lane] = az[ct];
      redC[(w * 4 + ct) * 64 + lane] = ar[ct];
    }
    __syncthreads();
    f32x4 Sz = redB[(0 * 4 + w) * 64 + lane];
    Sz += redB[(1 * 4 + w) * 64 + lane];
    Sz += redB[(2 * 4 + w) * 64 + lane];
    Sz += redB[(3 * 4 + w) * 64 + lane];
    f32x4 Sr = redC[(0 * 4 + w) * 64 + lane];
    Sr += redC[(1 * 4 + w) * 64 + lane];
    Sr += redC[(2 * 4 + w) * 64 + lane];
    Sr += redC[(3 * 4 + w) * 64 + lane];

#pragma unroll
    for (int j = 0; j < 4; ++j) {
      float zv = sigmoid_fast(Sz[j] + bf2f(xz_u[j]));
      float rv = sigmoid_fast(Sr[j] + bf2f(xr_u[j]));
      zreg[j] = zv;
      st_dw(spB + j * 4, ((unsigned)f2bf(rv * hreg[j]) << 16) | tagn);
    }
  }

  // epilogue: final h fp32 (plain stores; visible at kernel boundary)
#pragma unroll
  for (int j = 0; j < 4; ++j)
    hfinal[(size_t)(brow0 + j) * HH + hcol] = hreg[j];
}

// ============================================================================
// K5: out[b][o] = dot(h[b,:], Wo[o,:]) + bo[o]   (fp32)
// ============================================================================
__global__ void __launch_bounds__(256) k_out(const float* __restrict__ hf,
                                             const float* __restrict__ Wo,
                                             const float* __restrict__ bo,
                                             float* __restrict__ out) {
  __shared__ float hs[HH];
  const int b = blockIdx.x, tid = threadIdx.x;
  *(f32x4*)&hs[tid * 4] = *(const f32x4*)(hf + (size_t)b * HH + tid * 4);
  __syncthreads();
  float acc = bo[tid];
  const f32x4* wr = (const f32x4*)(Wo + (size_t)tid * HH);
#pragma unroll 8
  for (int k = 0; k < HH / 4; ++k) {
    f32x4 wv = wr[k];
    f32x4 hv = *(const f32x4*)&hs[k * 4];
    acc += wv[0] * hv[0] + wv[1] * hv[1] + wv[2] * hv[2] + wv[3] * hv[3];
  }
  out[(size_t)b * NOUT + tid] = acc;
}

// ============================================================================
extern "C" void kernel_launch(void* const* d_in, const int* in_sizes, int n_in,
                              void* d_out, int out_size, void* d_ws, size_t ws_size,
                              hipStream_t stream) {
  (void)in_sizes; (void)n_in; (void)out_size; (void)ws_size;
  const float* X  = (const float*)d_in[0];
  const float* Wx = (const float*)d_in[1];
  const float* bx = (const float*)d_in[2];
  const float* Wh = (const float*)d_in[3];
  const float* Uz = (const float*)d_in[4];
  const float* bz = (const float*)d_in[5];
  const float* Vz = (const float*)d_in[6];
  const float* Ur = (const float*)d_in[7];
  const float* br = (const float*)d_in[8];
  const float* Vr = (const float*)d_in[9];
  const float* Wo = (const float*)d_in[10];
  const float* bo = (const float*)d_in[11];

  char* ws = (char*)d_ws;
  unsigned short* XHp = (unsigned short*)(ws + OFF_XH);
  unsigned short* XZp = (unsigned short*)(ws + OFF_XZ);
  unsigned short* XRp = (unsigned short*)(ws + OFF_XR);
  unsigned short* Xb  = (unsigned short*)(ws + OFF_XB);
  unsigned short* Whp = (unsigned short*)(ws + OFF_WHP);
  unsigned short* Vzp = (unsigned short*)(ws + OFF_VZP);
  unsigned short* Vrp = (unsigned short*)(ws + OFF_VRP);
  unsigned short* Wxp = (unsigned short*)(ws + OFF_WXP);
  unsigned short* Uzp = (unsigned short*)(ws + OFF_UZP);
  unsigned short* Urp = (unsigned short*)(ws + OFF_URP);
  unsigned* hbp  = (unsigned*)(ws + OFF_HB);
  unsigned* hrbp = (unsigned*)(ws + OFF_HRB);
  float* hfp = (float*)(ws + OFF_HF);

  k_convert_x<<<8192, 256, 0, stream>>>(X, Xb);
  k_pack_w<<<dim3(512, 6), 256, 0, stream>>>(Wh, Vz, Vr, Wx, Uz, Ur,
                                             Whp, Vzp, Vrp, Wxp, Uzp, Urp);
  k_proj<<<dim3(512, 16, 3), 256, 0, stream>>>(Xb, Wxp, Uzp, Urp, bx, bz, br,
                                               XHp, XZp, XRp);
  k_scan<<<64, 256, 0, stream>>>(XHp, XZp, XRp, Whp, Vzp, Vrp,
                                 hbp, hrbp, hfp);
  k_out<<<64, 256, 0, stream>>>(hfp, Wo, bo, (float*)d_out);
}